// Round 12
// baseline (537.561 us; speedup 1.0000x reference)
//
#include <hip/hip_runtime.h>
#include <hip/hip_bf16.h>
#include <stdint.h>

typedef _Float16 h16;
typedef h16 h16x2 __attribute__((ext_vector_type(2)));
typedef h16 h16x8 __attribute__((ext_vector_type(8)));
typedef float f32x4 __attribute__((ext_vector_type(4)));

#define HF 128          // hidden/feature dim
#define EPS 1e-5f
#define BSH 9           // bucket shift: 512 rows per bucket
#define BROWS 512
#define BCAP 16384      // fixed bucket capacity (mean 8704, huge margin for this input)
#define ECHUNK 8192     // edges per workgroup in bucket passes
#define SBANKS 8        // stats atomic banks (contention /8)

union pk32 { uint32_t u; h16x2 h; };

static __device__ __forceinline__ uint32_t pack_h16(float a, float b) {
    pk32 c;
    c.h[0] = (h16)a; c.h[1] = (h16)b;
    return c.u;
}

static __device__ __forceinline__ float sum8(const float* __restrict__ st, int idx) {
    float s = 0.f;
#pragma unroll
    for (int b = 0; b < SBANKS; b++) s += st[b * 256 + idx];
    return s;
}

// device-coherent banked sum (used inside the persistent kernel after the grid barrier)
static __device__ __forceinline__ float sum8_coh(const float* st, int idx) {
    float s = 0.f;
#pragma unroll
    for (int b = 0; b < SBANKS; b++)
        s += __hip_atomic_load(&st[b * 256 + idx], __ATOMIC_RELAXED, __HIP_MEMORY_SCOPE_AGENT);
    return s;
}

// ---------------- bucketed CSR build (fixed-capacity buckets) ----------------

__global__ __launch_bounds__(256) void k_bscatter(const int* __restrict__ src,
                                                  const int* __restrict__ dst,
                                                  int* __restrict__ gcursor,
                                                  int2* __restrict__ staging, int ne, int nb) {
    __shared__ int h[128], gb[128];
    const int tid = threadIdx.x;
    if (tid < nb) h[tid] = 0;
    __syncthreads();
    const int beg = blockIdx.x * ECHUNK;
    const int end = min(beg + ECHUNK, ne);
    for (int i = beg + tid; i < end; i += 256)
        atomicAdd(&h[dst[i] >> BSH], 1);
    __syncthreads();
    if (tid < nb) {
        int c = h[tid];
        gb[tid] = c ? atomicAdd(&gcursor[tid], c) : 0;   // within-bucket offset
        h[tid] = 0;
    }
    __syncthreads();
    for (int i = beg + tid; i < end; i += 256) {
        int d = dst[i];
        int b = d >> BSH;
        int r = atomicAdd(&h[b], 1);
        staging[(size_t)b * BCAP + gb[b] + r] = make_int2(src[i], d);
    }
}

__global__ __launch_bounds__(256) void k_bbuild(const int2* __restrict__ staging,
                                                const int* __restrict__ gcursor,
                                                int* __restrict__ rowbeg,
                                                int* __restrict__ rowend,
                                                float* __restrict__ deginv,
                                                int* __restrict__ csrsrc, int n) {
    __shared__ int hist[BROWS];
    __shared__ int scan[BROWS];
    const int b = blockIdx.x;
    const int tid = threadIdx.x;
    const int rb = b << BSH;
    const int nrows = min(BROWS, n - rb);
    const int base = b * BCAP;
    const int cnt = gcursor[b];
    hist[tid] = 0; hist[tid + 256] = 0;
    __syncthreads();
    for (int i = tid; i < cnt; i += 256)
        atomicAdd(&hist[staging[base + i].y - rb], 1);
    __syncthreads();
    const int i0 = tid, i1 = tid + 256;
    scan[i0] = hist[i0]; scan[i1] = hist[i1];
    __syncthreads();
    for (int off = 1; off < BROWS; off <<= 1) {
        int v0 = (i0 >= off) ? scan[i0 - off] : 0;
        int v1 = (i1 >= off) ? scan[i1 - off] : 0;
        __syncthreads();
        scan[i0] += v0; scan[i1] += v1;
        __syncthreads();
    }
    for (int r = tid; r < BROWS; r += 256) {
        int c = hist[r];
        int excl = scan[r] - c;
        if (r < nrows) {
            rowbeg[rb + r] = base + excl;
            rowend[rb + r] = base + excl + c;
            deginv[rb + r] = c ? 1.0f / (float)c : 0.f;
        }
        scan[r] = excl;
    }
    __syncthreads();
    for (int i = tid; i < cnt; i += 256) {
        int2 e = staging[base + i];
        int pos = atomicAdd(&scan[e.y - rb], 1);
        csrsrc[base + pos] = e.x;
    }
}

// ---------------- prep: W transpose+swizzle fp16 (blocks 0..383) | feats->fp16 (rest) ----
// W element (col r, k) -> hw offset r*128 + ((k>>3) ^ (r&7))*8 + (k&7)
__global__ __launch_bounds__(256) void k_prep(const float* __restrict__ W1,
                                              const float* __restrict__ W2,
                                              h16* __restrict__ wp,
                                              const float* __restrict__ feats,
                                              uint32_t* __restrict__ hbuf, long tot2) {
    const int bid = (int)blockIdx.x;
    if (bid < 384) {
        const int mat = bid >> 6;                         // 0..5
        const int idx = ((bid & 63) << 8) + (int)threadIdx.x;
        const int l = mat >> 1;
        const float* Wsrc = (mat & 1) ? (W2 + l * 16384) : (W1 + l * 16384);
        const int nn = idx >> 7, k = idx & 127;
        float w = Wsrc[k * 128 + nn];
        int pos = nn * 128 + ((((k >> 3) ^ (nn & 7))) << 3) + (k & 7);
        wp[mat * 16384 + pos] = (h16)w;
    } else {
        long i = (long)(bid - 384) * 256 + threadIdx.x;
        if (i < tot2) {
            float2 v = ((const float2*)feats)[i];
            hbuf[i] = pack_h16(v.x, v.y);
        }
    }
}

// ---------------- SpMM: pooled = mean-gather(op(h)), packed-fp16 accumulate ----------
template <int AFF>
__global__ __launch_bounds__(256) void k_spmm(const uint32_t* __restrict__ hp,
                                              const int* __restrict__ rowbeg,
                                              const int* __restrict__ rowend,
                                              const float* __restrict__ deginv,
                                              const float* __restrict__ st,
                                              const float* __restrict__ g,
                                              const float* __restrict__ be,
                                              float inv_n,
                                              const int* __restrict__ csrsrc,
                                              uint32_t* __restrict__ pooled, int n, int np) {
    const int wid  = (int)((blockIdx.x * 256u + threadIdx.x) >> 6);
    const int lane = threadIdx.x & 63;
    if (wid >= np) return;
    uint32_t* outp = pooled + (size_t)wid * 64 + lane;
    if (wid >= n) { *outp = 0u; return; }   // zero pad rows
    h16x2 s2 = (h16x2)(h16)1.f, c2 = (h16x2)(h16)0.f;
    if (AFF) {
        const int c0 = lane * 2, c1 = c0 + 1;
        float m0 = sum8(st, c0) * inv_n, v0 = sum8(st, 128 + c0) * inv_n - m0 * m0;
        float sx = g[c0] * rsqrtf(v0 + EPS), cx = be[c0] - m0 * sx;
        float m1 = sum8(st, c1) * inv_n, v1 = sum8(st, 128 + c1) * inv_n - m1 * m1;
        float sy = g[c1] * rsqrtf(v1 + EPS), cy = be[c1] - m1 * sy;
        s2[0] = (h16)sx; s2[1] = (h16)sy;
        c2[0] = (h16)cx; c2[1] = (h16)cy;
    }
    const h16 z0 = (h16)0.f;
    h16x2 acc = (h16x2)z0;
    const int beg = rowbeg[wid], end = rowend[wid];
    for (int base = beg; base < end; base += 64) {
        const int rem = end - base;
        const int cnt = rem < 64 ? rem : 64;
        const int off = lane < cnt ? lane : cnt - 1;
        const int idx = csrsrc[base + off];          // coalesced block of indices
        int j = 0;
        for (; j + 16 <= cnt; j += 16) {
            uint32_t p[16];
#pragma unroll
            for (int u = 0; u < 16; u++) {
                int s = __builtin_amdgcn_readlane(idx, j + u);
                p[u] = hp[(size_t)s * 64 + lane];
            }
#pragma unroll
            for (int u = 0; u < 16; u++) {
                pk32 w; w.u = p[u];
                h16x2 v = w.h;
                if (AFF) {
                    v = v * s2 + c2;
                    v[0] = v[0] > z0 ? v[0] : z0;
                    v[1] = v[1] > z0 ? v[1] : z0;
                }
                acc = acc + v;
            }
        }
        for (; j < cnt; j++) {
            int s = __builtin_amdgcn_readlane(idx, j);
            pk32 w; w.u = hp[(size_t)s * 64 + lane];
            h16x2 v = w.h;
            if (AFF) {
                v = v * s2 + c2;
                v[0] = v[0] > z0 ? v[0] : z0;
                v[1] = v[1] > z0 ? v[1] : z0;
            }
            acc = acc + v;
        }
    }
    const float di = deginv[wid];
    *outp = pack_h16((float)acc[0] * di, (float)acc[1] * di);
}

// ---------------- fused MLP: z = relu(bn(pooled@W1+b1))@W2+b2, stats fused ----------
// One persistent kernel per layer; 391 blocks, 2 blocks/CU guaranteed co-resident.
// Phase A: GEMM1 from global pooled -> acc; y-stats atomics; y -> LDS (fp16, swizzled).
// Grid barrier (W2 DMA overlaps the spin).
// Phase B: affine from global stats; GEMM2 from LDS y-tile; z + z-stats out.
__global__ __launch_bounds__(256, 2) void k_mlp(const uint32_t* __restrict__ Ap,
                                                const h16* __restrict__ Wp1,
                                                const h16* __restrict__ Wp2,
                                                const float* __restrict__ b1v,
                                                const float* __restrict__ b2v,
                                                const float* __restrict__ g1v,
                                                const float* __restrict__ be1v,
                                                float* __restrict__ stY,
                                                float* __restrict__ stZ,
                                                float inv_n,
                                                h16* __restrict__ Z,
                                                int* __restrict__ ctr, int n) {
    __shared__ __align__(16) h16 WT[128 * 128];    // 32 KB: W1, then W2
    __shared__ __align__(16) h16 YT[128 * 128];    // 32 KB: y tile (swizzled)
    __shared__ float sred[4][128];
    __shared__ float sred2[4][128];
    __shared__ float aff[256];
    const int tid = threadIdx.x;
    const int wave = tid >> 6, lane = tid & 63;
    const int lrow = lane & 15, quad = lane >> 4;
    const int bx = (int)blockIdx.x * 128;
    const int sw = lrow & 7;
    const int bank = (int)(blockIdx.x & (SBANKS - 1));

    // DMA W1 -> WT
    {
        const char* gsrc = (const char*)Wp1 + wave * 1024 + lane * 16;
        char* ldst = (char*)&WT[0] + wave * 1024;
#pragma unroll
        for (int i = 0; i < 8; i++)
            __builtin_amdgcn_global_load_lds(
                (const __attribute__((address_space(1))) uint32_t*)(gsrc + i * 4096),
                (__attribute__((address_space(3))) uint32_t*)(ldst + i * 4096),
                16, 0, 0);
    }

    int mb[2];
    mb[0] = bx + wave * 16;
    mb[1] = bx + 64 + wave * 16;

    // A-frags from global pooled (packed fp16 rows of 64 uint32)
    h16x8 ah[2][4];
#pragma unroll
    for (int rt = 0; rt < 2; rt++) {
        const uint32_t* arow = Ap + (size_t)(mb[rt] + lrow) * 64 + quad * 4;
#pragma unroll
        for (int kt = 0; kt < 4; kt++) {
            uint4 r = *(const uint4*)(arow + kt * 16);
            ah[rt][kt] = *(const h16x8*)&r;
        }
    }

    __syncthreads();   // drain W1 DMA

    f32x4 acc[2][8];
#pragma unroll
    for (int rt = 0; rt < 2; rt++)
#pragma unroll
        for (int nt = 0; nt < 8; nt++) acc[rt][nt] = (f32x4){0.f, 0.f, 0.f, 0.f};
#pragma unroll
    for (int nt = 0; nt < 8; nt++) {
        const h16* wbase = &WT[(nt * 16 + lrow) * 128];
#pragma unroll
        for (int kt = 0; kt < 4; kt++) {
            h16x8 bh = *(const h16x8*)(wbase + (((4 * kt + quad) ^ sw) << 3));
#pragma unroll
            for (int rt = 0; rt < 2; rt++)
                acc[rt][nt] = __builtin_amdgcn_mfma_f32_16x16x32_f16(ah[rt][kt], bh, acc[rt][nt], 0, 0, 0);
        }
    }

    // epilogue 1: y -> LDS (swizzled), y-stats -> banked atomics
#pragma unroll
    for (int nt = 0; nt < 8; nt++) {
        int col = nt * 16 + lrow;
        float bv = b1v[col];
        float csum = 0.f, csq = 0.f;
#pragma unroll
        for (int rt = 0; rt < 2; rt++) {
#pragma unroll
            for (int r = 0; r < 4; r++) {
                int lr = wave * 16 + rt * 64 + quad * 4 + r;   // local row
                float yv = acc[rt][nt][r] + bv;
                YT[lr * 128 + ((((col >> 3) ^ (lr & 7))) << 3) + (col & 7)] = (h16)yv;
                if (bx + lr < n) { csum += yv; csq += yv * yv; }
            }
        }
        csum += __shfl_xor(csum, 16, 64); csum += __shfl_xor(csum, 32, 64);
        csq  += __shfl_xor(csq,  16, 64); csq  += __shfl_xor(csq,  32, 64);
        if (quad == 0) { sred[wave][col] = csum; sred2[wave][col] = csq; }
    }
    __syncthreads();
    if (tid < 128) {
        atomicAdd(&stY[bank * 256 + tid],       sred[0][tid] + sred[1][tid] + sred[2][tid] + sred[3][tid]);
        atomicAdd(&stY[bank * 256 + 128 + tid], sred2[0][tid] + sred2[1][tid] + sred2[2][tid] + sred2[3][tid]);
    }
    __syncthreads();   // WT1 fully consumed; safe to overwrite

    // DMA W2 -> WT (overlaps barrier spin)
    {
        const char* gsrc = (const char*)Wp2 + wave * 1024 + lane * 16;
        char* ldst = (char*)&WT[0] + wave * 1024;
#pragma unroll
        for (int i = 0; i < 8; i++)
            __builtin_amdgcn_global_load_lds(
                (const __attribute__((address_space(1))) uint32_t*)(gsrc + i * 4096),
                (__attribute__((address_space(3))) uint32_t*)(ldst + i * 4096),
                16, 0, 0);
    }

    // grid barrier
    __threadfence();
    if (tid == 0) {
        __hip_atomic_fetch_add(ctr, 1, __ATOMIC_ACQ_REL, __HIP_MEMORY_SCOPE_AGENT);
        while (__hip_atomic_load(ctr, __ATOMIC_ACQUIRE, __HIP_MEMORY_SCOPE_AGENT) < (int)gridDim.x)
            __builtin_amdgcn_s_sleep(8);
    }
    __syncthreads();   // all waves past barrier; W2 DMA drained (vmcnt 0)

    // inner BN affine from globally-summed y-stats
    if (tid < 128) {
        float m = sum8_coh(stY, tid) * inv_n;
        float v = sum8_coh(stY, 128 + tid) * inv_n - m * m;
        float a = g1v[tid] * rsqrtf(v + EPS);
        aff[tid] = a;
        aff[128 + tid] = be1v[tid] - m * a;
    }
    __syncthreads();

    // phase B: A-frags from LDS y-tile with affine+relu
#pragma unroll
    for (int rt = 0; rt < 2; rt++) {
#pragma unroll
        for (int kt = 0; kt < 4; kt++) {
            int m = wave * 16 + rt * 64 + lrow;    // local row
            h16x8 yv8 = *(const h16x8*)&YT[m * 128 + (((kt * 4 + quad) ^ (m & 7)) << 3)];
            h16x8 t;
#pragma unroll
            for (int j = 0; j < 8; j++) {
                int k = kt * 32 + quad * 8 + j;
                float x = fmaxf(fmaf((float)yv8[j], aff[k], aff[128 + k]), 0.f);
                t[j] = (h16)x;
            }
            ah[rt][kt] = t;
        }
    }

#pragma unroll
    for (int rt = 0; rt < 2; rt++)
#pragma unroll
        for (int nt = 0; nt < 8; nt++) acc[rt][nt] = (f32x4){0.f, 0.f, 0.f, 0.f};
#pragma unroll
    for (int nt = 0; nt < 8; nt++) {
        const h16* wbase = &WT[(nt * 16 + lrow) * 128];
#pragma unroll
        for (int kt = 0; kt < 4; kt++) {
            h16x8 bh = *(const h16x8*)(wbase + (((4 * kt + quad) ^ sw) << 3));
#pragma unroll
            for (int rt = 0; rt < 2; rt++)
                acc[rt][nt] = __builtin_amdgcn_mfma_f32_16x16x32_f16(ah[rt][kt], bh, acc[rt][nt], 0, 0, 0);
        }
    }

    // epilogue 2: z -> global fp16, z-stats -> banked atomics
#pragma unroll
    for (int nt = 0; nt < 8; nt++) {
        int col = nt * 16 + lrow;
        float bv = b2v[col];
        float csum = 0.f, csq = 0.f;
#pragma unroll
        for (int rt = 0; rt < 2; rt++) {
#pragma unroll
            for (int r = 0; r < 4; r++) {
                int row = mb[rt] + quad * 4 + r;
                float zv = acc[rt][nt][r] + bv;
                Z[(size_t)row * 128 + col] = (h16)zv;
                if (row < n) { csum += zv; csq += zv * zv; }
            }
        }
        csum += __shfl_xor(csum, 16, 64); csum += __shfl_xor(csum, 32, 64);
        csq  += __shfl_xor(csq,  16, 64); csq  += __shfl_xor(csq,  32, 64);
        if (quad == 0) { sred[wave][col] = csum; sred2[wave][col] = csq; }
    }
    __syncthreads();
    if (tid < 128) {
        atomicAdd(&stZ[bank * 256 + tid],       sred[0][tid] + sred[1][tid] + sred[2][tid] + sred[3][tid]);
        atomicAdd(&stZ[bank * 256 + 128 + tid], sred2[0][tid] + sred2[1][tid] + sred2[2][tid] + sred2[3][tid]);
    }
}

// ---------------- final BN+ReLU: packed-fp16 z -> fp32 out (affine from banked stats) ----
__global__ __launch_bounds__(256) void k_bnrelu(const uint32_t* __restrict__ Z,
                                                const float* __restrict__ st,
                                                const float* __restrict__ g,
                                                const float* __restrict__ be,
                                                float inv_n,
                                                float* __restrict__ out, long tot2) {
    long i = (long)blockIdx.x * 256 + threadIdx.x;
    if (i >= tot2) return;
    int c = (int)((i * 2) & 127);
    float m0 = sum8(st, c) * inv_n,     v0 = sum8(st, 128 + c) * inv_n - m0 * m0;
    float a0 = g[c] * rsqrtf(v0 + EPS),     c0 = be[c] - m0 * a0;
    float m1 = sum8(st, c + 1) * inv_n, v1 = sum8(st, 129 + c) * inv_n - m1 * m1;
    float a1 = g[c + 1] * rsqrtf(v1 + EPS), c1 = be[c + 1] - m1 * a1;
    pk32 w; w.u = Z[i];
    float2 o;
    o.x = fmaxf(fmaf((float)w.h[0], a0, c0), 0.f);
    o.y = fmaxf(fmaf((float)w.h[1], a1, c1), 0.f);
    ((float2*)out)[i] = o;
}

// ---------------- launch ----------------
extern "C" void kernel_launch(void* const* d_in, const int* in_sizes, int n_in,
                              void* d_out, int out_size, void* d_ws, size_t ws_size,
                              hipStream_t stream) {
    const float* feats = (const float*)d_in[0];
    const float* W1    = (const float*)d_in[1];
    const float* b1    = (const float*)d_in[2];
    const float* g1    = (const float*)d_in[3];
    const float* be1   = (const float*)d_in[4];
    const float* W2    = (const float*)d_in[5];
    const float* b2    = (const float*)d_in[6];
    const float* og    = (const float*)d_in[7];
    const float* ob    = (const float*)d_in[8];
    const int*   src   = (const int*)d_in[9];
    const int*   dst   = (const int*)d_in[10];

    const int n  = in_sizes[0] / HF;         // 50000 nodes
    const int ne = in_sizes[9];              // 850000 edges (incl self loops)
    const int np = (n + 127) & ~127;         // pad to 128-row GEMM blocks
    const int nb = (n + BROWS - 1) >> BSH;   // 98 buckets (<=128)

    char* p = (char*)d_ws;
    auto alloc = [&](size_t bytes) -> char* {
        char* r = p;
        p += (bytes + 511) & ~(size_t)511;
        return r;
    };
    uint32_t* hbuf    = (uint32_t*)alloc((size_t)np * 64 * 4);    // packed fp16 feats
    uint32_t* pooled  = (uint32_t*)alloc((size_t)np * 64 * 4);    // packed fp16 pooled
    uint32_t* zb      = (uint32_t*)alloc((size_t)np * 64 * 4);    // packed fp16 z
    h16*      wprep   = (h16*)     alloc(6 * 16384 * 2);          // swizzled fp16 W^T x6
    float*    deginv  = (float*)   alloc((size_t)n * 4);
    int*      rowbeg  = (int*)     alloc((size_t)n * 4);
    int*      rowend  = (int*)     alloc((size_t)n * 4);
    int*      csrsrc  = (int*)     alloc((size_t)nb * BCAP * 4);
    int2*     staging = (int2*)    alloc((size_t)nb * BCAP * 8);
    // zero zone: gcursor (nb ints) + barrier ctrs (3) + 6 banked stats slots
    char*     zone    = alloc(1024 + 6 * SBANKS * 256 * 4);
    int*      gcursor = (int*)zone;
    int*      bctr    = (int*)(zone + 512);
    float*    stats6  = (float*)(zone + 1024);

    hipMemsetAsync(zone, 0, 1024 + 6 * SBANKS * 256 * 4, stream);

    const long tot2  = (long)n * (HF / 2);
    const int bnb    = (int)((tot2 + 255) / 256);
    const int spmmb  = np / 4;
    const int gemmb  = np / 128;
    const float inv_n = 1.0f / (float)n;
    const int ebk = (ne + ECHUNK - 1) / ECHUNK;
    const int SL = SBANKS * 256;

    k_prep    <<<384 + bnb, 256, 0, stream>>>(W1, W2, wprep, feats, hbuf, tot2);
    k_bscatter<<<ebk, 256, 0, stream>>>(src, dst, gcursor, staging, ne, nb);
    k_bbuild  <<<nb, 256, 0, stream>>>(staging, gcursor, rowbeg, rowend, deginv, csrsrc, n);

    for (int l = 0; l < 3; l++) {
        float* sY = stats6 + (2 * l) * SL;       // y-stats slot (banked)
        float* sZ = stats6 + (2 * l + 1) * SL;   // z-stats slot (banked)
        if (l == 0)
            k_spmm<0><<<spmmb, 256, 0, stream>>>(hbuf, rowbeg, rowend, deginv,
                                                 nullptr, nullptr, nullptr, inv_n,
                                                 csrsrc, pooled, n, np);
        else
            k_spmm<1><<<spmmb, 256, 0, stream>>>(zb, rowbeg, rowend, deginv,
                                                 stats6 + (2 * (l - 1) + 1) * SL,
                                                 og + (l - 1) * HF, ob + (l - 1) * HF, inv_n,
                                                 csrsrc, pooled, n, np);
        k_mlp<<<gemmb, 256, 0, stream>>>(pooled,
                                         wprep + (size_t)(2 * l) * 16384,
                                         wprep + (size_t)(2 * l + 1) * 16384,
                                         b1 + l * HF, b2 + l * HF,
                                         g1 + l * HF, be1 + l * HF,
                                         sY, sZ, inv_n,
                                         (h16*)zb, bctr + l, n);
    }
    k_bnrelu<<<bnb, 256, 0, stream>>>(zb, stats6 + 5 * SL, og + 2 * HF, ob + 2 * HF,
                                      inv_n, (float*)d_out, tot2);
}

// Round 13
// 380.316 us; speedup vs baseline: 1.4135x; 1.4135x over previous
//
#include <hip/hip_runtime.h>
#include <hip/hip_bf16.h>
#include <stdint.h>

typedef _Float16 h16;
typedef h16 h16x2 __attribute__((ext_vector_type(2)));
typedef h16 h16x8 __attribute__((ext_vector_type(8)));
typedef float f32x4 __attribute__((ext_vector_type(4)));

#define HF 128          // hidden/feature dim
#define EPS 1e-5f
#define BSH 9           // bucket shift: 512 rows per bucket
#define BROWS 512
#define BCAP 16384      // fixed bucket capacity (mean 8704, huge margin for this input)
#define ECHUNK 8192     // edges per workgroup in bucket passes
#define SBANKS 8        // stats atomic banks (contention /8)

union pk32 { uint32_t u; h16x2 h; };

static __device__ __forceinline__ uint32_t pack_h16(float a, float b) {
    pk32 c;
    c.h[0] = (h16)a; c.h[1] = (h16)b;
    return c.u;
}

static __device__ __forceinline__ float sum8(const float* __restrict__ st, int idx) {
    float s = 0.f;
#pragma unroll
    for (int b = 0; b < SBANKS; b++) s += st[b * 256 + idx];
    return s;
}

// ---------------- fused front kernel: edge scatter | W prep | feats cvt ----------------
// blocks [0, ebk): LDS-binned scatter of (src,dst) into fixed-capacity bucket staging
// blocks [ebk, ebk+384): W transpose+swizzle -> fp16 (6 mats); element (col r,k) ->
//   r*128 + ((k>>3)^(r&7))*8 + (k&7)
// blocks [ebk+384, ...): feats fp32 -> packed fp16
__global__ __launch_bounds__(256) void k_front(const int* __restrict__ src,
                                               const int* __restrict__ dst,
                                               int* __restrict__ gcursor,
                                               int2* __restrict__ staging, int ne, int nb,
                                               const float* __restrict__ W1,
                                               const float* __restrict__ W2,
                                               h16* __restrict__ wp,
                                               const float* __restrict__ feats,
                                               uint32_t* __restrict__ hbuf, long tot2,
                                               int ebk) {
    __shared__ int h[128], gb[128];
    const int bid = (int)blockIdx.x;
    const int tid = threadIdx.x;
    if (bid < ebk) {
        if (tid < nb) h[tid] = 0;
        __syncthreads();
        const int beg = bid * ECHUNK;
        const int end = min(beg + ECHUNK, ne);
        for (int i = beg + tid; i < end; i += 256)
            atomicAdd(&h[dst[i] >> BSH], 1);
        __syncthreads();
        if (tid < nb) {
            int c = h[tid];
            gb[tid] = c ? atomicAdd(&gcursor[tid], c) : 0;   // within-bucket offset
            h[tid] = 0;
        }
        __syncthreads();
        for (int i = beg + tid; i < end; i += 256) {
            int d = dst[i];
            int b = d >> BSH;
            int r = atomicAdd(&h[b], 1);
            staging[(size_t)b * BCAP + gb[b] + r] = make_int2(src[i], d);
        }
    } else if (bid < ebk + 384) {
        const int wb = bid - ebk;
        const int mat = wb >> 6;                          // 0..5
        const int idx = ((wb & 63) << 8) + tid;
        const int l = mat >> 1;
        const float* Wsrc = (mat & 1) ? (W2 + l * 16384) : (W1 + l * 16384);
        const int nn = idx >> 7, k = idx & 127;
        float w = Wsrc[k * 128 + nn];
        int pos = nn * 128 + ((((k >> 3) ^ (nn & 7))) << 3) + (k & 7);
        wp[mat * 16384 + pos] = (h16)w;
    } else {
        long i = (long)(bid - ebk - 384) * 256 + tid;
        if (i < tot2) {
            float2 v = ((const float2*)feats)[i];
            hbuf[i] = pack_h16(v.x, v.y);
        }
    }
}

// ---------------- bucket build: rowbeg/rowend/deginv + csrsrc ----------------
__global__ __launch_bounds__(256) void k_bbuild(const int2* __restrict__ staging,
                                                const int* __restrict__ gcursor,
                                                int* __restrict__ rowbeg,
                                                int* __restrict__ rowend,
                                                float* __restrict__ deginv,
                                                int* __restrict__ csrsrc, int n) {
    __shared__ int hist[BROWS];
    __shared__ int scan[BROWS];
    const int b = blockIdx.x;
    const int tid = threadIdx.x;
    const int rb = b << BSH;
    const int nrows = min(BROWS, n - rb);
    const int base = b * BCAP;
    const int cnt = gcursor[b];
    hist[tid] = 0; hist[tid + 256] = 0;
    __syncthreads();
    for (int i = tid; i < cnt; i += 256)
        atomicAdd(&hist[staging[base + i].y - rb], 1);
    __syncthreads();
    const int i0 = tid, i1 = tid + 256;
    scan[i0] = hist[i0]; scan[i1] = hist[i1];
    __syncthreads();
    for (int off = 1; off < BROWS; off <<= 1) {
        int v0 = (i0 >= off) ? scan[i0 - off] : 0;
        int v1 = (i1 >= off) ? scan[i1 - off] : 0;
        __syncthreads();
        scan[i0] += v0; scan[i1] += v1;
        __syncthreads();
    }
    for (int r = tid; r < BROWS; r += 256) {
        int c = hist[r];
        int excl = scan[r] - c;
        if (r < nrows) {
            rowbeg[rb + r] = base + excl;
            rowend[rb + r] = base + excl + c;
            deginv[rb + r] = c ? 1.0f / (float)c : 0.f;
        }
        scan[r] = excl;
    }
    __syncthreads();
    for (int i = tid; i < cnt; i += 256) {
        int2 e = staging[base + i];
        int pos = atomicAdd(&scan[e.y - rb], 1);
        csrsrc[base + pos] = e.x;
    }
}

// ---------------- SpMM: pooled = mean-gather(op(h)), packed-fp16 accumulate ----------
template <int AFF>
__global__ __launch_bounds__(256) void k_spmm(const uint32_t* __restrict__ hp,
                                              const int* __restrict__ rowbeg,
                                              const int* __restrict__ rowend,
                                              const float* __restrict__ deginv,
                                              const float* __restrict__ st,
                                              const float* __restrict__ g,
                                              const float* __restrict__ be,
                                              float inv_n,
                                              const int* __restrict__ csrsrc,
                                              uint32_t* __restrict__ pooled, int n, int np) {
    const int wid  = (int)((blockIdx.x * 256u + threadIdx.x) >> 6);
    const int lane = threadIdx.x & 63;
    if (wid >= np) return;
    uint32_t* outp = pooled + (size_t)wid * 64 + lane;
    if (wid >= n) { *outp = 0u; return; }   // zero pad rows
    h16x2 s2 = (h16x2)(h16)1.f, c2 = (h16x2)(h16)0.f;
    if (AFF) {
        const int c0 = lane * 2, c1 = c0 + 1;
        float m0 = sum8(st, c0) * inv_n, v0 = sum8(st, 128 + c0) * inv_n - m0 * m0;
        float sx = g[c0] * rsqrtf(v0 + EPS), cx = be[c0] - m0 * sx;
        float m1 = sum8(st, c1) * inv_n, v1 = sum8(st, 128 + c1) * inv_n - m1 * m1;
        float sy = g[c1] * rsqrtf(v1 + EPS), cy = be[c1] - m1 * sy;
        s2[0] = (h16)sx; s2[1] = (h16)sy;
        c2[0] = (h16)cx; c2[1] = (h16)cy;
    }
    const h16 z0 = (h16)0.f;
    h16x2 acc = (h16x2)z0;
    const int beg = rowbeg[wid], end = rowend[wid];
    for (int base = beg; base < end; base += 64) {
        const int rem = end - base;
        const int cnt = rem < 64 ? rem : 64;
        const int off = lane < cnt ? lane : cnt - 1;
        const int idx = csrsrc[base + off];          // coalesced block of indices
        int j = 0;
        for (; j + 16 <= cnt; j += 16) {
            uint32_t p[16];
#pragma unroll
            for (int u = 0; u < 16; u++) {
                int s = __builtin_amdgcn_readlane(idx, j + u);
                p[u] = hp[(size_t)s * 64 + lane];
            }
#pragma unroll
            for (int u = 0; u < 16; u++) {
                pk32 w; w.u = p[u];
                h16x2 v = w.h;
                if (AFF) {
                    v = v * s2 + c2;
                    v[0] = v[0] > z0 ? v[0] : z0;
                    v[1] = v[1] > z0 ? v[1] : z0;
                }
                acc = acc + v;
            }
        }
        for (; j < cnt; j++) {
            int s = __builtin_amdgcn_readlane(idx, j);
            pk32 w; w.u = hp[(size_t)s * 64 + lane];
            h16x2 v = w.h;
            if (AFF) {
                v = v * s2 + c2;
                v[0] = v[0] > z0 ? v[0] : z0;
                v[1] = v[1] > z0 ? v[1] : z0;
            }
            acc = acc + v;
        }
    }
    const float di = deginv[wid];
    *outp = pack_h16((float)acc[0] * di, (float)acc[1] * di);
}

// ---------------- GEMM: Y = op(A) @ W + bias, fp16 MFMA, fused banked column stats ----
// 64-row tiles (grid ~782 -> ~3 blocks/CU for latency overlap across blocks).
// W: pre-transposed, pre-swizzled fp16 (k_front), DMA'd to LDS via global_load_lds.
// MODE 0: A packed fp16 (pooled), used directly.
// MODE 1: A packed fp16 (y) + fused relu(a*s+c) (inner BN affine from banked stats).
// Output packed fp16; stats computed in fp32 from accumulators (exact).
template <int MODE>
__global__ __launch_bounds__(256) void k_gemm(const uint32_t* __restrict__ Ap,
                                              const h16* __restrict__ Wp,
                                              const float* __restrict__ bias,
                                              const float* __restrict__ st,
                                              const float* __restrict__ g,
                                              const float* __restrict__ be,
                                              float inv_n,
                                              h16* __restrict__ Y,
                                              float* __restrict__ outstats, int n) {
    __shared__ __align__(16) h16 WT[128 * 128];   // swizzled W^T, stride 128 (32 KB)
    __shared__ float sred[4][128];
    __shared__ float sred2[4][128];
    __shared__ float aff[256];
    const int tid = threadIdx.x;
    const int wave = tid >> 6, lane = tid & 63;

    // async DMA: 8 x (4 waves x 64 lanes x 16B) = 32 KB
    {
        const char* gsrc = (const char*)Wp + wave * 1024 + lane * 16;
        char* ldst = (char*)&WT[0] + wave * 1024;
#pragma unroll
        for (int i = 0; i < 8; i++) {
            __builtin_amdgcn_global_load_lds(
                (const __attribute__((address_space(1))) uint32_t*)(gsrc + i * 4096),
                (__attribute__((address_space(3))) uint32_t*)(ldst + i * 4096),
                16, 0, 0);
        }
    }
    if (MODE == 1 && tid < 128) {
        float m = sum8(st, tid) * inv_n;
        float v = sum8(st, 128 + tid) * inv_n - m * m;
        float a = g[tid] * rsqrtf(v + EPS);
        aff[tid] = a;
        aff[128 + tid] = be[tid] - m * a;
    }

    const int lrow = lane & 15, quad = lane >> 4;
    const int mbase = (int)blockIdx.x * 64 + wave * 16;

    // A-fragment: A[m=lane&15][k=quad*8+j]; packed rows of 64 uint32
    uint4 araw[4];
    {
        const uint32_t* arow = Ap + (size_t)(mbase + lrow) * 64 + quad * 4;
#pragma unroll
        for (int kt = 0; kt < 4; kt++)
            araw[kt] = *(const uint4*)(arow + kt * 16);
    }

    __syncthreads();   // drains DMA + aff visible

    h16x8 ah[4];
#pragma unroll
    for (int kt = 0; kt < 4; kt++) {
        if (MODE == 0) {
            ah[kt] = *(const h16x8*)&araw[kt];
        } else {
            const uint32_t* pw = (const uint32_t*)&araw[kt];
            h16x8 t;
#pragma unroll
            for (int j2 = 0; j2 < 4; j2++) {
                pk32 w; w.u = pw[j2];
                int k = kt * 32 + quad * 8 + j2 * 2;
                float x0 = fmaxf(fmaf((float)w.h[0], aff[k],     aff[128 + k]), 0.f);
                float x1 = fmaxf(fmaf((float)w.h[1], aff[k + 1], aff[129 + k]), 0.f);
                t[2 * j2]     = (h16)x0;
                t[2 * j2 + 1] = (h16)x1;
            }
            ah[kt] = t;
        }
    }

    f32x4 acc[8];
#pragma unroll
    for (int nt = 0; nt < 8; nt++) acc[nt] = (f32x4){0.f, 0.f, 0.f, 0.f};

    const int sw = lrow & 7;
#pragma unroll
    for (int nt = 0; nt < 8; nt++) {
        const h16* wbase = &WT[(nt * 16 + lrow) * 128];
#pragma unroll
        for (int kt = 0; kt < 4; kt++) {
            h16x8 bh = *(const h16x8*)(wbase + (((4 * kt + quad) ^ sw) << 3));
            acc[nt] = __builtin_amdgcn_mfma_f32_16x16x32_f16(ah[kt], bh, acc[nt], 0, 0, 0);
        }
    }

    // C/D layout: col = lane&15, row = quad*4 + reg  [verified m89]
#pragma unroll
    for (int nt = 0; nt < 8; nt++) {
        int col = nt * 16 + lrow;
        float bv = bias[col];
        float csum = 0.f, csq = 0.f;
#pragma unroll
        for (int r = 0; r < 4; r++) {
            int row = mbase + quad * 4 + r;
            float yv = acc[nt][r] + bv;
            Y[(size_t)row * 128 + col] = (h16)yv;
            if (row < n) { csum += yv; csq += yv * yv; }
        }
        csum += __shfl_xor(csum, 16, 64); csum += __shfl_xor(csum, 32, 64);
        csq  += __shfl_xor(csq,  16, 64); csq  += __shfl_xor(csq,  32, 64);
        if (quad == 0) { sred[wave][col] = csum; sred2[wave][col] = csq; }
    }
    __syncthreads();
    if (tid < 128) {
        float s = sred[0][tid] + sred[1][tid] + sred[2][tid] + sred[3][tid];
        float q = sred2[0][tid] + sred2[1][tid] + sred2[2][tid] + sred2[3][tid];
        const int bank = (int)(blockIdx.x & (SBANKS - 1));
        atomicAdd(&outstats[bank * 256 + tid], s);
        atomicAdd(&outstats[bank * 256 + 128 + tid], q);
    }
}

// ---------------- final BN+ReLU: packed-fp16 z -> fp32 out (affine from banked stats) ----
__global__ __launch_bounds__(256) void k_bnrelu(const uint32_t* __restrict__ Z,
                                                const float* __restrict__ st,
                                                const float* __restrict__ g,
                                                const float* __restrict__ be,
                                                float inv_n,
                                                float* __restrict__ out, long tot2) {
    long i = (long)blockIdx.x * 256 + threadIdx.x;
    if (i >= tot2) return;
    int c = (int)((i * 2) & 127);
    float m0 = sum8(st, c) * inv_n,     v0 = sum8(st, 128 + c) * inv_n - m0 * m0;
    float a0 = g[c] * rsqrtf(v0 + EPS),     c0 = be[c] - m0 * a0;
    float m1 = sum8(st, c + 1) * inv_n, v1 = sum8(st, 129 + c) * inv_n - m1 * m1;
    float a1 = g[c + 1] * rsqrtf(v1 + EPS), c1 = be[c + 1] - m1 * a1;
    pk32 w; w.u = Z[i];
    float2 o;
    o.x = fmaxf(fmaf((float)w.h[0], a0, c0), 0.f);
    o.y = fmaxf(fmaf((float)w.h[1], a1, c1), 0.f);
    ((float2*)out)[i] = o;
}

// ---------------- launch ----------------
extern "C" void kernel_launch(void* const* d_in, const int* in_sizes, int n_in,
                              void* d_out, int out_size, void* d_ws, size_t ws_size,
                              hipStream_t stream) {
    const float* feats = (const float*)d_in[0];
    const float* W1    = (const float*)d_in[1];
    const float* b1    = (const float*)d_in[2];
    const float* g1    = (const float*)d_in[3];
    const float* be1   = (const float*)d_in[4];
    const float* W2    = (const float*)d_in[5];
    const float* b2    = (const float*)d_in[6];
    const float* og    = (const float*)d_in[7];
    const float* ob    = (const float*)d_in[8];
    const int*   src   = (const int*)d_in[9];
    const int*   dst   = (const int*)d_in[10];

    const int n  = in_sizes[0] / HF;         // 50000 nodes
    const int ne = in_sizes[9];              // 850000 edges (incl self loops)
    const int np = (n + 63) & ~63;           // pad to 64-row GEMM blocks
    const int nb = (n + BROWS - 1) >> BSH;   // 98 buckets (<=128)

    char* p = (char*)d_ws;
    auto alloc = [&](size_t bytes) -> char* {
        char* r = p;
        p += (bytes + 511) & ~(size_t)511;
        return r;
    };
    uint32_t* hbuf    = (uint32_t*)alloc((size_t)np * 64 * 4);    // packed fp16 feats
    uint32_t* pooled  = (uint32_t*)alloc((size_t)np * 64 * 4);    // packed fp16 pooled
    uint32_t* ybuf    = (uint32_t*)alloc((size_t)np * 64 * 4);    // packed fp16 y
    uint32_t* zb      = (uint32_t*)alloc((size_t)np * 64 * 4);    // packed fp16 z
    h16*      wprep   = (h16*)     alloc(6 * 16384 * 2);          // swizzled fp16 W^T x6
    float*    deginv  = (float*)   alloc((size_t)n * 4);
    int*      rowbeg  = (int*)     alloc((size_t)n * 4);
    int*      rowend  = (int*)     alloc((size_t)n * 4);
    int*      csrsrc  = (int*)     alloc((size_t)nb * BCAP * 4);
    int2*     staging = (int2*)    alloc((size_t)nb * BCAP * 8);
    // zero zone: gcursor (nb ints) + 6 banked stats slots
    char*     zone    = alloc(512 + 6 * SBANKS * 256 * 4);
    int*      gcursor = (int*)zone;
    float*    stats6  = (float*)(zone + 512);

    hipMemsetAsync(zone, 0, 512 + 6 * SBANKS * 256 * 4, stream);

    const long tot2  = (long)n * (HF / 2);
    const int bnb    = (int)((tot2 + 255) / 256);
    const int spmmb  = np / 4;
    const int gemmb  = np / 64;
    const float inv_n = 1.0f / (float)n;
    const int ebk = (ne + ECHUNK - 1) / ECHUNK;
    const int SL = SBANKS * 256;

    k_front <<<ebk + 384 + bnb, 256, 0, stream>>>(src, dst, gcursor, staging, ne, nb,
                                                  W1, W2, wprep, feats, hbuf, tot2, ebk);
    k_bbuild<<<nb, 256, 0, stream>>>(staging, gcursor, rowbeg, rowend, deginv, csrsrc, n);

    for (int l = 0; l < 3; l++) {
        float* sY = stats6 + (2 * l) * SL;       // y-stats slot (banked)
        float* sZ = stats6 + (2 * l + 1) * SL;   // z-stats slot (banked)
        if (l == 0)
            k_spmm<0><<<spmmb, 256, 0, stream>>>(hbuf, rowbeg, rowend, deginv,
                                                 nullptr, nullptr, nullptr, inv_n,
                                                 csrsrc, pooled, n, np);
        else
            k_spmm<1><<<spmmb, 256, 0, stream>>>(zb, rowbeg, rowend, deginv,
                                                 stats6 + (2 * (l - 1) + 1) * SL,
                                                 og + (l - 1) * HF, ob + (l - 1) * HF, inv_n,
                                                 csrsrc, pooled, n, np);
        k_gemm<0><<<gemmb, 256, 0, stream>>>(pooled,
                                             wprep + (size_t)(2 * l) * 16384,
                                             b1 + l * HF,
                                             nullptr, nullptr, nullptr, inv_n,
                                             (h16*)ybuf, sY, n);
        k_gemm<1><<<gemmb, 256, 0, stream>>>(ybuf,
                                             wprep + (size_t)(2 * l + 1) * 16384,
                                             b2 + l * HF,
                                             sY, g1 + l * HF, be1 + l * HF, inv_n,
                                             (h16*)zb, sZ, n);
    }
    k_bnrelu<<<bnb, 256, 0, stream>>>(zb, stats6 + 5 * SL, og + 2 * HF, ob + 2 * HF,
                                      inv_n, (float*)d_out, tot2);
}